// Round 6
// baseline (279.246 us; speedup 1.0000x reference)
//
#include <hip/hip_runtime.h>
#include <cstdint>
#include <cstddef>

typedef __bf16 bf16x8 __attribute__((ext_vector_type(8)));
typedef float f32x4 __attribute__((ext_vector_type(4)));
typedef float f32x16 __attribute__((ext_vector_type(16)));
typedef unsigned short u16x4 __attribute__((ext_vector_type(4)));
typedef unsigned int u32x4 __attribute__((ext_vector_type(4)));

// fp32 -> bf16 round-to-nearest-even
__device__ __forceinline__ unsigned short f2bf(float f) {
  union { float f; unsigned u; } v; v.f = f;
  unsigned r = (v.u + 0x7FFF + ((v.u >> 16) & 1)) >> 16;
  return (unsigned short)r;
}

// pack two floats into one u32 of 2 bf16
__device__ __forceinline__ unsigned pkbf(float x, float y) {
  unsigned short a = __builtin_bit_cast(unsigned short, (__bf16)x);
  unsigned short b = __builtin_bit_cast(unsigned short, (__bf16)y);
  return (unsigned)a | ((unsigned)b << 16);
}

// async global->LDS, 16B per lane
__device__ __forceinline__ void gl2lds16(const void* g, void* l) {
  __builtin_amdgcn_global_load_lds(
      (const __attribute__((address_space(1))) void*)g,
      (__attribute__((address_space(3))) void*)l,
      16, 0, 0);
}

// ---------------------------------------------------------------- fused prep
__global__ __launch_bounds__(256) void prep_fused(
    const float* __restrict__ x, unsigned short* __restrict__ xb,
    const float* __restrict__ Wqkv, unsigned short* __restrict__ WqkvT,
    const float* __restrict__ Wo, unsigned short* __restrict__ WoT,
    const int* __restrict__ mask, int* __restrict__ kmax) {
  __shared__ float t[32][33];
  const int bid = blockIdx.x, tid = threadIdx.x;
  if (bid < 4096) {
    size_t i = ((size_t)bid * 256 + tid) * 4;
#pragma unroll
    for (int c = 0; c < 2; ++c) {
      float4 v = *(const float4*)(x + i);
      u16x4 o;
      o[0] = f2bf(v.x); o[1] = f2bf(v.y); o[2] = f2bf(v.z); o[3] = f2bf(v.w);
      *(u16x4*)(xb + i) = o;
      i += (size_t)4096 * 256 * 4;
    }
  } else if (bid < 4096 + 3072) {
    const int b2 = bid - 4096;
    const int c0 = (b2 % 96) * 32, r0 = (b2 / 96) * 32;
    const int tx = tid & 31, ty = tid >> 5;
#pragma unroll
    for (int j = 0; j < 4; ++j)
      t[ty + j * 8][tx] = Wqkv[(size_t)(r0 + ty + j * 8) * 3072 + c0 + tx];
    __syncthreads();
#pragma unroll
    for (int j = 0; j < 4; ++j)
      WqkvT[(size_t)(c0 + ty + j * 8) * 1024 + r0 + tx] = f2bf(t[tx][ty + j * 8]);
  } else if (bid < 8192) {
    const int b3 = bid - (4096 + 3072);
    const int c0 = (b3 & 31) * 32, r0 = (b3 >> 5) * 32;
    const int tx = tid & 31, ty = tid >> 5;
#pragma unroll
    for (int j = 0; j < 4; ++j)
      t[ty + j * 8][tx] = Wo[(size_t)(r0 + ty + j * 8) * 1024 + c0 + tx];
    __syncthreads();
#pragma unroll
    for (int j = 0; j < 4; ++j)
      WoT[(size_t)(c0 + ty + j * 8) * 1024 + r0 + tx] = f2bf(t[tx][ty + j * 8]);
  } else {
    const int i = (bid - 8192) * 256 + tid;
    int mv = mask[i];
    int key = mv ? 0 : ((i & 2047) + 1);
#pragma unroll
    for (int off = 32; off; off >>= 1) key = max(key, __shfl_xor(key, off, 64));
    if ((tid & 63) == 0) atomicMax(&kmax[i >> 11], key);
  }
}

// ---------------------------------------------------------------- GEMM (C = A[M,K] * B[N,K]^T)
// Round 6: 256x256 tile, BK=64, 8 waves (2M x 4N, 128x64 out each), 2 LDS
// buffers (64KB each), 4 phases per K-step, 2 barriers per K-step with
// COUNTED vmcnt (2 / 4, never 0 mid-loop).
// Key invariant making per-wave vmcnt sound with shared LDS: COLOCATED
// staging — each wave stages exactly the A-half (rows wm*128..+127) and
// B-band (rows wn*64..+63) that IT reads; stage issue order (A01,A23,B01,B23)
// matches read order (P0: As0+Bs0, P1: As1, P2: Bs1, P3: As0 re-read), so
// vmcnt(2) at the K-step boundary covers everything P0/P1 needs and vmcnt(4)
// at mid covers Bs1; co-readers of a region executed the identical wait
// before the same barrier.
template <int EPI>
__global__ __launch_bounds__(512, 2) void gemm_bt(
    const unsigned short* __restrict__ A, const unsigned short* __restrict__ Bm,
    const float* __restrict__ bias, float* __restrict__ outF,
    unsigned short* __restrict__ Qb, unsigned short* __restrict__ Kb,
    unsigned short* __restrict__ Vt, int M, int N, int K, int NB) {
  extern __shared__ unsigned short lds[];  // 2 x (A[256][64] + B[256][64]) els
  const int tid = threadIdx.x;
  // XCD-bijective swizzle (nwg % 8 == 0 for both dispatches)
  const int nwg = gridDim.x;
  const int cpx = nwg >> 3;
  const int wg = (blockIdx.x & 7) * cpx + (blockIdx.x >> 3);
  const int bm = (wg / NB) * 256;
  const int bn = (wg % NB) * 256;
  const int wave = tid >> 6, lane = tid & 63;
  const int wm = wave >> 2, wn = wave & 3;     // 2 m-waves x 4 n-waves
  const int lr = lane & 15, lq = lane >> 4;
  const int r8 = lane >> 3, s8 = lane & 7;
  const int srcsl = (s8 ^ r8) << 3;            // pre-swizzled col slot (els)
  const int NT = K >> 6;

  f32x4 acc[8][4] = {};

  const unsigned short* Ag = A + (size_t)bm * K;
  const unsigned short* Bg = Bm + (size_t)bn * K;
  const int aRowBase = wm * 128 + wn * 8 + r8;   // + j*32  (row%8 == r8)
  const int bRowBase = wn * 64 + wm * 8 + r8;    // + j*16  (row%8 == r8)
  const int aDstBase = (wm * 128 + wn * 8) * 64 + lane * 8;
  const int bDstBase = 16384 + (wn * 64 + wm * 8) * 64 + lane * 8;

  auto stA = [&](int buf, int k0, int j) {
    gl2lds16(Ag + (size_t)(aRowBase + j * 32) * K + k0 + srcsl,
             lds + buf * 32768 + aDstBase + j * 2048);
  };
  auto stB = [&](int buf, int k0, int j) {
    gl2lds16(Bg + (size_t)(bRowBase + j * 16) * K + k0 + srcsl,
             lds + buf * 32768 + bDstBase + j * 1024);
  };

  const int rsl = lr & 7;
  auto rdA = [&](int buf, int mi, int ks) {
    return *(const bf16x8*)(lds + buf * 32768 + (wm * 128 + mi * 16 + lr) * 64 +
                            ((((ks << 2) | lq) ^ rsl) << 3));
  };
  auto rdB = [&](int buf, int nj, int ks) {
    return *(const bf16x8*)(lds + buf * 32768 + 16384 + (wn * 64 + nj * 16 + lr) * 64 +
                            ((((ks << 2) | lq) ^ rsl) << 3));
  };

  // prologue: stage tile 0 in canonical order A01,A23,B01,B23
  stA(0, 0, 0); stA(0, 0, 1);
  stA(0, 0, 2); stA(0, 0, 3);
  stB(0, 0, 0); stB(0, 0, 1);
  stB(0, 0, 2); stB(0, 0, 3);

  int cur = 0;
  for (int T = 0; T < NT; ++T) {
    const bool pf = (T + 1 < NT);
    const int kn = (T + 1) << 6;
    // ---- K-step boundary: own A01,A23,B01(T) landed (B23(T) stays in flight)
    asm volatile("s_waitcnt lgkmcnt(0)" ::: "memory");
    asm volatile("s_waitcnt vmcnt(2)" ::: "memory");
    __builtin_amdgcn_s_barrier();
    __builtin_amdgcn_sched_barrier(0);
    // ---- P0: quadrant (mi0-3, nj0-1)
    if (pf) { stA(cur ^ 1, kn, 0); stA(cur ^ 1, kn, 1); }
    bf16x8 a0[4][2], b0[2][2];
#pragma unroll
    for (int mi = 0; mi < 4; ++mi)
#pragma unroll
      for (int ks = 0; ks < 2; ++ks) a0[mi][ks] = rdA(cur, mi, ks);
#pragma unroll
    for (int nj = 0; nj < 2; ++nj)
#pragma unroll
      for (int ks = 0; ks < 2; ++ks) b0[nj][ks] = rdB(cur, nj, ks);
    __builtin_amdgcn_s_setprio(1);
#pragma unroll
    for (int mi = 0; mi < 4; ++mi)
#pragma unroll
      for (int nj = 0; nj < 2; ++nj)
#pragma unroll
        for (int ks = 0; ks < 2; ++ks)
          acc[mi][nj] = __builtin_amdgcn_mfma_f32_16x16x32_bf16(a0[mi][ks], b0[nj][ks], acc[mi][nj], 0, 0, 0);
    __builtin_amdgcn_s_setprio(0);
    // ---- P1: quadrant (mi4-7, nj0-1)
    if (pf) { stA(cur ^ 1, kn, 2); stA(cur ^ 1, kn, 3); }
    bf16x8 a1[4][2];
#pragma unroll
    for (int mi = 0; mi < 4; ++mi)
#pragma unroll
      for (int ks = 0; ks < 2; ++ks) a1[mi][ks] = rdA(cur, 4 + mi, ks);
    __builtin_amdgcn_s_setprio(1);
#pragma unroll
    for (int mi = 0; mi < 4; ++mi)
#pragma unroll
      for (int nj = 0; nj < 2; ++nj)
#pragma unroll
        for (int ks = 0; ks < 2; ++ks)
          acc[4 + mi][nj] = __builtin_amdgcn_mfma_f32_16x16x32_bf16(a1[mi][ks], b0[nj][ks], acc[4 + mi][nj], 0, 0, 0);
    __builtin_amdgcn_s_setprio(0);
    // ---- mid barrier: B23(T) landed
    asm volatile("s_waitcnt lgkmcnt(0)" ::: "memory");
    if (pf) asm volatile("s_waitcnt vmcnt(4)" ::: "memory");
    else    asm volatile("s_waitcnt vmcnt(0)" ::: "memory");
    __builtin_amdgcn_s_barrier();
    __builtin_amdgcn_sched_barrier(0);
    // ---- P2: quadrant (mi4-7, nj2-3)
    if (pf) { stB(cur ^ 1, kn, 0); stB(cur ^ 1, kn, 1); }
    bf16x8 b1[2][2];
#pragma unroll
    for (int nj = 0; nj < 2; ++nj)
#pragma unroll
      for (int ks = 0; ks < 2; ++ks) b1[nj][ks] = rdB(cur, 2 + nj, ks);
    __builtin_amdgcn_s_setprio(1);
#pragma unroll
    for (int mi = 0; mi < 4; ++mi)
#pragma unroll
      for (int nj = 0; nj < 2; ++nj)
#pragma unroll
        for (int ks = 0; ks < 2; ++ks)
          acc[4 + mi][2 + nj] = __builtin_amdgcn_mfma_f32_16x16x32_bf16(a1[mi][ks], b1[nj][ks], acc[4 + mi][2 + nj], 0, 0, 0);
    __builtin_amdgcn_s_setprio(0);
    // ---- P3: quadrant (mi0-3, nj2-3), re-read As0
    if (pf) { stB(cur ^ 1, kn, 2); stB(cur ^ 1, kn, 3); }
    bf16x8 a0b[4][2];
#pragma unroll
    for (int mi = 0; mi < 4; ++mi)
#pragma unroll
      for (int ks = 0; ks < 2; ++ks) a0b[mi][ks] = rdA(cur, mi, ks);
    __builtin_amdgcn_s_setprio(1);
#pragma unroll
    for (int mi = 0; mi < 4; ++mi)
#pragma unroll
      for (int nj = 0; nj < 2; ++nj)
#pragma unroll
        for (int ks = 0; ks < 2; ++ks)
          acc[mi][2 + nj] = __builtin_amdgcn_mfma_f32_16x16x32_bf16(a0b[mi][ks], b1[nj][ks], acc[mi][2 + nj], 0, 0, 0);
    __builtin_amdgcn_s_setprio(0);
    cur ^= 1;
  }

#pragma unroll
  for (int mi = 0; mi < 8; ++mi) {
#pragma unroll
    for (int nj = 0; nj < 4; ++nj) {
#pragma unroll
      for (int r = 0; r < 4; ++r) {
        int m = bm + wm * 128 + mi * 16 + lq * 4 + r;
        int n = bn + wn * 64 + nj * 16 + lr;
        float v = acc[mi][nj][r] + bias[n];
        if (EPI == 0) {
          int b = m >> 11, t = m & 2047;
          int part = n >> 10, d = n & 1023;
          int h = d >> 6, hd = d & 63;
          size_t qk = ((size_t)(b * 16 + h) * 2048 + t) * 64 + hd;
          // fold softmax scale 1/sqrt(64) and log2(e) into Q
          if (part == 0)      Qb[qk] = f2bf(v * 0.18033688011112042f);
          else if (part == 1) Kb[qk] = f2bf(v);
          else                Vt[((size_t)(b * 16 + h) * 64 + hd) * 2048 + t] = f2bf(v);
        } else {
          outF[(size_t)m * N + n] = v;
        }
      }
    }
  }
}

// ---------------------------------------------------------------- flash attention
// (unchanged from round 4/5)
__global__ __launch_bounds__(256, 4) void flash_attn(
    const unsigned short* __restrict__ Qb, const unsigned short* __restrict__ Kb,
    const unsigned short* __restrict__ Vt, const int* __restrict__ kmax,
    unsigned short* __restrict__ ctx) {
  __shared__ unsigned short lds[16384];  // [buf][ K 4096 | V 4096 ] elements

  const int bid = blockIdx.x;            // 1024 blocks
  const int halfg = bid >> 9;            // 0/1
  const int rb = bid & 511;
  const int bh = rb & 63;                // bid%8 == bh%8 -> XCD locality
  const int j0 = rb >> 6;                // 0..7
  const int j = halfg ? (15 - j0) : j0;  // q-superblock 0..15, paired for balance
  const int blockQ = j << 7;             // 128 q-rows per block
  const int b = bh >> 4, h = bh & 15;
  const int tid = threadIdx.x;
  const int wave = tid >> 6, lane = tid & 63;
  const int l31 = lane & 31, hi = lane >> 5;
  const int qw = blockQ + wave * 32;     // wave's 32 q-rows

  const unsigned short* Qh = Qb + (size_t)bh * 2048 * 64;
  const unsigned short* Kh = Kb + (size_t)bh * 2048 * 64;
  const unsigned short* Vh = Vt + (size_t)bh * 64 * 2048;
  unsigned short* ctxBase = ctx + (size_t)b * 2048 * 1024 + h * 64;

  const int kmaxRaw = kmax[b];
  const int kcapC = (kmaxRaw + 63) >> 6;
  const int lastB = min((blockQ + 127) >> 6, kcapC - 1);
  const int diagI = qw >> 6;

  bf16x8 qf[4];
#pragma unroll
  for (int ds = 0; ds < 4; ++ds)
    qf[ds] = *(const bf16x8*)(Qh + (size_t)(qw + l31) * 64 + ds * 16 + hi * 8);

  f32x16 O[2] = {};
  float mR = -1e30f, lR = 0.f;

  const int trow = tid >> 3, tslot = tid & 7;

  auto stage = [&](int bufI, int kcS) {
#pragma unroll
    for (int rnd = 0; rnd < 2; ++rnd) {
      int row = rnd * 32 + trow;
      int sl = tslot ^ (row & 7);
      gl2lds16(Kh + (size_t)(kcS + row) * 64 + sl * 8,
               lds + bufI * 8192 + rnd * 2048 + tid * 8);
      gl2lds16(Vh + (size_t)row * 2048 + kcS + sl * 8,
               lds + bufI * 8192 + 4096 + rnd * 2048 + tid * 8);
    }
  };

  stage(0, 0);
  int cur = 0;
  for (int i = 0; i <= lastB; ++i) {
    __syncthreads();
    if (i < lastB) stage(cur ^ 1, (i + 1) << 6);
    if (i <= diagI) {
      const int kc = i << 6;
      const unsigned short* Ksb = lds + cur * 8192;
      const unsigned short* Vsb = Ksb + 4096;

      f32x16 S[2] = {};
      __builtin_amdgcn_s_setprio(1);
#pragma unroll
      for (int kt = 0; kt < 2; ++kt) {
        const int row = kt * 32 + l31;
        const int rx = row & 7;
#pragma unroll
        for (int ds = 0; ds < 4; ++ds) {
          bf16x8 kfr = *(const bf16x8*)(Ksb + row * 64 + (((ds * 2 + hi) ^ rx) << 3));
          S[kt] = __builtin_amdgcn_mfma_f32_32x32x16_bf16(kfr, qf[ds], S[kt], 0, 0, 0);
        }
      }
      __builtin_amdgcn_s_setprio(0);

      const bool isDiag = (i == diagI);
      if (isDiag || (kc + 64 > kmaxRaw)) {
        const int q = qw + l31;
#pragma unroll
        for (int kt = 0; kt < 2; ++kt)
#pragma unroll
          for (int rr = 0; rr < 16; ++rr) {
            int key = kc + kt * 32 + (rr & 3) + ((rr >> 2) << 3) + (hi << 2);
            if ((isDiag && key > q) || key >= kmaxRaw) S[kt][rr] = -1e30f;
          }
      }

      {
        float v[16];
#pragma unroll
        for (int rr = 0; rr < 16; ++rr) v[rr] = fmaxf(S[0][rr], S[1][rr]);
#pragma unroll
        for (int st = 8; st; st >>= 1)
#pragma unroll
          for (int rr = 0; rr < st; ++rr) v[rr] = fmaxf(v[rr], v[rr + st]);
        float mx = fmaxf(v[0], __shfl_xor(v[0], 32, 64));
        float mnew = fmaxf(mR, mx);
        float a = __builtin_amdgcn_exp2f(mR - mnew);
        mR = mnew;
#pragma unroll
        for (int kt = 0; kt < 2; ++kt)
#pragma unroll
          for (int rr = 0; rr < 16; ++rr)
            S[kt][rr] = __builtin_amdgcn_exp2f(S[kt][rr] - mnew);
        float sacc[16];
#pragma unroll
        for (int rr = 0; rr < 16; ++rr) sacc[rr] = S[0][rr] + S[1][rr];
#pragma unroll
        for (int st = 8; st; st >>= 1)
#pragma unroll
          for (int rr = 0; rr < st; ++rr) sacc[rr] += sacc[rr + st];
        float sum = sacc[0] + __shfl_xor(sacc[0], 32, 64);
        lR = lR * a + sum;
#pragma unroll
        for (int mt = 0; mt < 2; ++mt)
#pragma unroll
          for (int rr = 0; rr < 16; ++rr) O[mt][rr] *= a;
      }
      bf16x8 pf[2][2];
#pragma unroll
      for (int kt = 0; kt < 2; ++kt) {
        unsigned a0 = pkbf(S[kt][0], S[kt][1]);
        unsigned a1 = pkbf(S[kt][2], S[kt][3]);
        unsigned b0 = pkbf(S[kt][4], S[kt][5]);
        unsigned b1 = pkbf(S[kt][6], S[kt][7]);
        unsigned c0 = pkbf(S[kt][8], S[kt][9]);
        unsigned c1 = pkbf(S[kt][10], S[kt][11]);
        unsigned d0 = pkbf(S[kt][12], S[kt][13]);
        unsigned d1 = pkbf(S[kt][14], S[kt][15]);
        unsigned s0 = __shfl_xor(hi ? a0 : b0, 32, 64);
        unsigned s1 = __shfl_xor(hi ? a1 : b1, 32, 64);
        unsigned s2 = __shfl_xor(hi ? c0 : d0, 32, 64);
        unsigned s3 = __shfl_xor(hi ? c1 : d1, 32, 64);
        u32x4 f0, f1;
        f0[0] = hi ? s0 : a0; f0[1] = hi ? s1 : a1;
        f0[2] = hi ? b0 : s0; f0[3] = hi ? b1 : s1;
        f1[0] = hi ? s2 : c0; f1[1] = hi ? s3 : c1;
        f1[2] = hi ? d0 : s2; f1[3] = hi ? d1 : s3;
        pf[kt][0] = __builtin_bit_cast(bf16x8, f0);
        pf[kt][1] = __builtin_bit_cast(bf16x8, f1);
      }

      __builtin_amdgcn_s_setprio(1);
      const int vx = l31 & 7;
#pragma unroll
      for (int kt = 0; kt < 2; ++kt)
#pragma unroll
        for (int ks = 0; ks < 2; ++ks) {
          const int slot = kt * 4 + ks * 2 + hi;
          bf16x8 v0 = *(const bf16x8*)(Vsb + l31 * 64 + ((slot ^ vx) << 3));
          bf16x8 v1 = *(const bf16x8*)(Vsb + (32 + l31) * 64 + ((slot ^ vx) << 3));
          O[0] = __builtin_amdgcn_mfma_f32_32x32x16_bf16(v0, pf[kt][ks], O[0], 0, 0, 0);
          O[1] = __builtin_amdgcn_mfma_f32_32x32x16_bf16(v1, pf[kt][ks], O[1], 0, 0, 0);
        }
      __builtin_amdgcn_s_setprio(0);
    }
    cur ^= 1;
  }

  {
    float linv = 1.0f / lR;
    const int q = qw + l31;
    unsigned short* cp = ctxBase + (size_t)q * 1024;
#pragma unroll
    for (int mt = 0; mt < 2; ++mt)
#pragma unroll
      for (int g = 0; g < 4; ++g) {
        u16x4 o4;
#pragma unroll
        for (int rr = 0; rr < 4; ++rr) o4[rr] = f2bf(O[mt][4 * g + rr] * linv);
        *(u16x4*)(cp + mt * 32 + 8 * g + 4 * hi) = o4;
      }
  }
}

// ---------------------------------------------------------------- launch
extern "C" void kernel_launch(void* const* d_in, const int* in_sizes, int n_in,
                              void* d_out, int out_size, void* d_ws, size_t ws_size,
                              hipStream_t stream) {
  const float* x    = (const float*)d_in[0];
  const float* Wqkv = (const float*)d_in[1];
  const float* bqkv = (const float*)d_in[2];
  const float* Wo   = (const float*)d_in[3];
  const float* bo   = (const float*)d_in[4];
  const int*   mask = (const int*)d_in[5];
  float* out = (float*)d_out;

  unsigned short* ws = (unsigned short*)d_ws;
  const size_t SZ_X = (size_t)8192 * 1024;  // B*T*D
  unsigned short* xb    = ws;                                   // 16 MB, reused as ctx
  unsigned short* WqkvT = xb + SZ_X;                            // 6 MB
  unsigned short* WoT   = WqkvT + (size_t)3072 * 1024;          // 2 MB
  unsigned short* Qb    = WoT + (size_t)1024 * 1024;            // 16 MB
  unsigned short* Kb    = Qb + SZ_X;                            // 16 MB
  unsigned short* Vt    = Kb + SZ_X;                            // 16 MB
  int*            kmax  = (int*)(Vt + SZ_X);                    // 16 B
  unsigned short* ctx   = xb;  // xb dead after GEMM1

  static bool inited = false;
  if (!inited) {
    hipFuncSetAttribute((const void*)gemm_bt<0>,
                        hipFuncAttributeMaxDynamicSharedMemorySize, 131072);
    hipFuncSetAttribute((const void*)gemm_bt<1>,
                        hipFuncAttributeMaxDynamicSharedMemorySize, 131072);
    inited = true;
  }

  hipMemsetAsync(kmax, 0, 4 * sizeof(int), stream);
  prep_fused<<<8224, 256, 0, stream>>>(x, xb, Wqkv, WqkvT, Wo, WoT, mask, kmax);
  gemm_bt<0><<<384, 512, 131072, stream>>>(xb, WqkvT, bqkv, nullptr, Qb, Kb, Vt,
                                           8192, 3072, 1024, 12);
  flash_attn<<<1024, 256, 0, stream>>>(Qb, Kb, Vt, kmax, ctx);
  gemm_bt<1><<<128, 512, 131072, stream>>>(ctx, WoT, bo, out, nullptr, nullptr, nullptr,
                                           8192, 1024, 1024, 4);
}

// Round 7
// 268.738 us; speedup vs baseline: 1.0391x; 1.0391x over previous
//
#include <hip/hip_runtime.h>
#include <cstdint>
#include <cstddef>

typedef __bf16 bf16x8 __attribute__((ext_vector_type(8)));
typedef float f32x4 __attribute__((ext_vector_type(4)));
typedef float f32x16 __attribute__((ext_vector_type(16)));
typedef unsigned short u16x4 __attribute__((ext_vector_type(4)));
typedef unsigned int u32x4 __attribute__((ext_vector_type(4)));

// fp32 -> bf16 round-to-nearest-even
__device__ __forceinline__ unsigned short f2bf(float f) {
  union { float f; unsigned u; } v; v.f = f;
  unsigned r = (v.u + 0x7FFF + ((v.u >> 16) & 1)) >> 16;
  return (unsigned short)r;
}

// pack two floats into one u32 of 2 bf16
__device__ __forceinline__ unsigned pkbf(float x, float y) {
  unsigned short a = __builtin_bit_cast(unsigned short, (__bf16)x);
  unsigned short b = __builtin_bit_cast(unsigned short, (__bf16)y);
  return (unsigned)a | ((unsigned)b << 16);
}

// async global->LDS, 16B per lane
__device__ __forceinline__ void gl2lds16(const void* g, void* l) {
  __builtin_amdgcn_global_load_lds(
      (const __attribute__((address_space(1))) void*)g,
      (__attribute__((address_space(3))) void*)l,
      16, 0, 0);
}

// ---------------------------------------------------------------- fused prep
// Round 7: mask branch writes per-block partial kmax (plain store, no atomics)
// -> the hipMemsetAsync launch is gone; flash maxes 8 partials per batch.
__global__ __launch_bounds__(256) void prep_fused(
    const float* __restrict__ x, unsigned short* __restrict__ xb,
    const float* __restrict__ Wqkv, unsigned short* __restrict__ WqkvT,
    const float* __restrict__ Wo, unsigned short* __restrict__ WoT,
    const int* __restrict__ mask, int* __restrict__ kparts) {
  __shared__ float t[32][33];
  __shared__ int wred[4];
  const int bid = blockIdx.x, tid = threadIdx.x;
  if (bid < 4096) {
    // cast x -> bf16, 2 chunks of 4 floats per thread
    size_t i = ((size_t)bid * 256 + tid) * 4;
#pragma unroll
    for (int c = 0; c < 2; ++c) {
      float4 v = *(const float4*)(x + i);
      u16x4 o;
      o[0] = f2bf(v.x); o[1] = f2bf(v.y); o[2] = f2bf(v.z); o[3] = f2bf(v.w);
      *(u16x4*)(xb + i) = o;
      i += (size_t)4096 * 256 * 4;
    }
  } else if (bid < 4096 + 3072) {
    // transpose+cast Wqkv [1024,3072] -> WqkvT [3072,1024]
    const int b2 = bid - 4096;
    const int c0 = (b2 % 96) * 32, r0 = (b2 / 96) * 32;
    const int tx = tid & 31, ty = tid >> 5;
#pragma unroll
    for (int j = 0; j < 4; ++j)
      t[ty + j * 8][tx] = Wqkv[(size_t)(r0 + ty + j * 8) * 3072 + c0 + tx];
    __syncthreads();
#pragma unroll
    for (int j = 0; j < 4; ++j)
      WqkvT[(size_t)(c0 + ty + j * 8) * 1024 + r0 + tx] = f2bf(t[tx][ty + j * 8]);
  } else if (bid < 8192) {
    // transpose+cast Wo [1024,1024] -> WoT
    const int b3 = bid - (4096 + 3072);
    const int c0 = (b3 & 31) * 32, r0 = (b3 >> 5) * 32;
    const int tx = tid & 31, ty = tid >> 5;
#pragma unroll
    for (int j = 0; j < 4; ++j)
      t[ty + j * 8][tx] = Wo[(size_t)(r0 + ty + j * 8) * 1024 + c0 + tx];
    __syncthreads();
#pragma unroll
    for (int j = 0; j < 4; ++j)
      WoT[(size_t)(c0 + ty + j * 8) * 1024 + r0 + tx] = f2bf(t[tx][ty + j * 8]);
  } else {
    // per-block (256 mask entries) max unpadded key index+1 -> kparts[32]
    const int bi = bid - 8192;           // 0..31, 8 blocks per batch
    const int i = bi * 256 + tid;
    int mv = mask[i];
    int key = mv ? 0 : ((i & 2047) + 1);
#pragma unroll
    for (int off = 32; off; off >>= 1) key = max(key, __shfl_xor(key, off, 64));
    if ((tid & 63) == 0) wred[tid >> 6] = key;
    __syncthreads();
    if (tid == 0)
      kparts[bi] = max(max(wred[0], wred[1]), max(wred[2], wred[3]));
  }
}

// ---------------------------------------------------------------- GEMM (C = A[M,K] * B[N,K]^T)
// Round 7: exact revert to the round-5 version (measured 80.6us / 639 TF, the
// documented 2-phase-class ceiling at K=1024). Round-6's coarse 4-phase split
// reproduced m196's documented -7..-27% regression (-23%): read->use
// serialization + extra barrier drains. BM=256 x BN=128 x BK=64, 512 threads
// (8 waves = 4m x 2n, 64x64 out each), THREE LDS buffers (48KB each),
// counted-vmcnt pipeline: wait vmcnt(6) (T+1's 6 loads stay in flight, never
// 0 mid-loop) -> barrier -> stage T+2 into buf[(T+2)%3] (occupant T-1
// provably dead). XOR swizzle on global source + ds_read side: 0 conflicts.
template <int EPI>
__global__ __launch_bounds__(512, 2) void gemm_bt(
    const unsigned short* __restrict__ A, const unsigned short* __restrict__ Bm,
    const float* __restrict__ bias, float* __restrict__ outF,
    unsigned short* __restrict__ Qb, unsigned short* __restrict__ Kb,
    unsigned short* __restrict__ Vt, int M, int N, int K) {
  extern __shared__ unsigned short lds[];  // 3 bufs x (A 16384 + B 8192) els
  const int tid = threadIdx.x;
  const int bm = blockIdx.x * 256;
  const int bn = blockIdx.y * 128;
  const int wave = tid >> 6, lane = tid & 63;
  const int wm4 = wave >> 1, wn2 = wave & 1;   // 4 m-waves x 2 n-waves
  const int lr = lane & 15, lq = lane >> 4;
  const int NT = K >> 6;

  f32x4 acc[4][4] = {};

  const int tr = tid >> 3, ts = tid & 7;
  const int srcsl = (ts ^ (tr & 7)) << 3;      // pre-swizzled col slot (els)

  auto stage = [&](int buf, int k0) {
#pragma unroll
    for (int r = 0; r < 4; ++r)
      gl2lds16(A + (size_t)(bm + r * 64 + tr) * K + k0 + srcsl,
               lds + buf * 24576 + r * 4096 + tid * 8);
#pragma unroll
    for (int r = 0; r < 2; ++r)
      gl2lds16(Bm + (size_t)(bn + r * 64 + tr) * K + k0 + srcsl,
               lds + buf * 24576 + 16384 + r * 4096 + tid * 8);
  };

  stage(0, 0);
  stage(1, 64);
  int bT = 0, bT2 = 2;
  const int rx = lr & 7;  // read-side swizzle key (row&7 == lr&7 here)
  for (int T = 0; T < NT; ++T) {
    if (T < NT - 1) {
      asm volatile("s_waitcnt vmcnt(6)" ::: "memory");
    } else {
      asm volatile("s_waitcnt vmcnt(0)" ::: "memory");
    }
    __builtin_amdgcn_s_barrier();
    __builtin_amdgcn_sched_barrier(0);
    if (T + 2 < NT) stage(bT2, (T + 2) << 6);
    const unsigned short* Ab = lds + bT * 24576;
    const unsigned short* Bb = Ab + 16384;
#pragma unroll
    for (int ks = 0; ks < 2; ++ks) {
      bf16x8 afr[4], bfr[4];
#pragma unroll
      for (int mi = 0; mi < 4; ++mi) {
        int row = wm4 * 64 + mi * 16 + lr;
        afr[mi] = *(const bf16x8*)(Ab + row * 64 + ((((ks << 2) | lq) ^ rx) << 3));
      }
#pragma unroll
      for (int nj = 0; nj < 4; ++nj) {
        int row = wn2 * 64 + nj * 16 + lr;
        bfr[nj] = *(const bf16x8*)(Bb + row * 64 + ((((ks << 2) | lq) ^ rx) << 3));
      }
      __builtin_amdgcn_s_setprio(1);
#pragma unroll
      for (int mi = 0; mi < 4; ++mi)
#pragma unroll
        for (int nj = 0; nj < 4; ++nj)
          acc[mi][nj] = __builtin_amdgcn_mfma_f32_16x16x32_bf16(afr[mi], bfr[nj], acc[mi][nj], 0, 0, 0);
      __builtin_amdgcn_s_setprio(0);
    }
    bT = (bT == 2) ? 0 : bT + 1;
    bT2 = (bT2 == 2) ? 0 : bT2 + 1;
  }

#pragma unroll
  for (int mi = 0; mi < 4; ++mi) {
#pragma unroll
    for (int nj = 0; nj < 4; ++nj) {
#pragma unroll
      for (int r = 0; r < 4; ++r) {
        int m = bm + wm4 * 64 + mi * 16 + lq * 4 + r;
        int n = bn + wn2 * 64 + nj * 16 + lr;
        float v = acc[mi][nj][r] + bias[n];
        if (EPI == 0) {
          int b = m >> 11, t = m & 2047;
          int part = n >> 10, d = n & 1023;
          int h = d >> 6, hd = d & 63;
          size_t qk = ((size_t)(b * 16 + h) * 2048 + t) * 64 + hd;
          // fold softmax scale 1/sqrt(64) and log2(e) into Q
          if (part == 0)      Qb[qk] = f2bf(v * 0.18033688011112042f);
          else if (part == 1) Kb[qk] = f2bf(v);
          else                Vt[((size_t)(b * 16 + h) * 64 + hd) * 2048 + t] = f2bf(v);
        } else {
          outF[(size_t)m * N + n] = v;
        }
      }
    }
  }
}

// ---------------------------------------------------------------- flash attention
// Round 7: T3/T4 for flash. Was: __syncthreads() per chunk = vmcnt(0)+lgkm(0)
// FULL drain of the just-issued next-chunk staging loads whenever compute
// (~400cy) < load latency. Now: 3-buffer ring (48KB LDS), chunk i+2 staged at
// iter i, and the barrier is raw s_barrier preceded by COUNTED vmcnt(4):
// exactly chunk i+1's 4 loads (the newest) stay in flight; vmcnt(4) => all
// older loads (chunk i) landed; barrier propagates the guarantee to other
// waves' staged data. Drain-0 only on the last iter. sched_barrier(0) after
// the barrier pins staging below it (buffer-reuse safety).
// Also T13 defer-max (THR=8): skip the O-rescale when the chunk max doesn't
// grow past mR+8; P bounded by 2^8, f32 l-accum absorbs it.
__global__ __launch_bounds__(256, 4) void flash_attn(
    const unsigned short* __restrict__ Qb, const unsigned short* __restrict__ Kb,
    const unsigned short* __restrict__ Vt, const int* __restrict__ kparts,
    unsigned short* __restrict__ ctx) {
  __shared__ unsigned short lds[24576];  // 3 bufs x [ K 4096 | V 4096 ] els

  const int bid = blockIdx.x;            // 1024 blocks
  const int halfg = bid >> 9;            // 0/1
  const int rb = bid & 511;
  const int bh = rb & 63;                // bid%8 == bh%8 -> XCD locality
  const int j0 = rb >> 6;                // 0..7
  const int j = halfg ? (15 - j0) : j0;  // q-superblock 0..15, paired for balance
  const int blockQ = j << 7;             // 128 q-rows per block
  const int b = bh >> 4, h = bh & 15;
  const int tid = threadIdx.x;
  const int wave = tid >> 6, lane = tid & 63;
  const int l31 = lane & 31, hi = lane >> 5;
  const int qw = blockQ + wave * 32;     // wave's 32 q-rows

  const unsigned short* Qh = Qb + (size_t)bh * 2048 * 64;
  const unsigned short* Kh = Kb + (size_t)bh * 2048 * 64;
  const unsigned short* Vh = Vt + (size_t)bh * 64 * 2048;
  unsigned short* ctxBase = ctx + (size_t)b * 2048 * 1024 + h * 64;

  int kmaxRaw = 0;
#pragma unroll
  for (int p = 0; p < 8; ++p) kmaxRaw = max(kmaxRaw, kparts[b * 8 + p]);
  const int kcapC = (kmaxRaw + 63) >> 6;
  const int lastB = min((blockQ + 127) >> 6, kcapC - 1);
  const int diagI = qw >> 6;

  bf16x8 qf[4];
#pragma unroll
  for (int ds = 0; ds < 4; ++ds)
    qf[ds] = *(const bf16x8*)(Qh + (size_t)(qw + l31) * 64 + ds * 16 + hi * 8);

  f32x16 O[2] = {};
  float mR = -1e30f, lR = 0.f;

  const int trow = tid >> 3, tslot = tid & 7;

  auto stage = [&](int bufI, int kcS) {
#pragma unroll
    for (int rnd = 0; rnd < 2; ++rnd) {
      int row = rnd * 32 + trow;
      int sl = tslot ^ (row & 7);
      gl2lds16(Kh + (size_t)(kcS + row) * 64 + sl * 8,
               lds + bufI * 8192 + rnd * 2048 + tid * 8);
      gl2lds16(Vh + (size_t)row * 2048 + kcS + sl * 8,
               lds + bufI * 8192 + 4096 + rnd * 2048 + tid * 8);
    }
  };

  stage(0, 0);
  if (lastB >= 1) stage(1, 64);
  int cb = 0, sb = 2;
  for (int i = 0; i <= lastB; ++i) {
    if (i < lastB) {
      asm volatile("s_waitcnt vmcnt(4)" ::: "memory");
    } else {
      asm volatile("s_waitcnt vmcnt(0)" ::: "memory");
    }
    __builtin_amdgcn_s_barrier();
    __builtin_amdgcn_sched_barrier(0);
    if (i + 2 <= lastB) stage(sb, (i + 2) << 6);
    if (i <= diagI) {
      const int kc = i << 6;
      const unsigned short* Ksb = lds + cb * 8192;
      const unsigned short* Vsb = Ksb + 4096;

      // ---- QK^T: S^T[key][q], A=K (m=key), B=Q^T (n=q)
      f32x16 S[2] = {};
      __builtin_amdgcn_s_setprio(1);
#pragma unroll
      for (int kt = 0; kt < 2; ++kt) {
        const int row = kt * 32 + l31;
        const int rxk = row & 7;
#pragma unroll
        for (int ds = 0; ds < 4; ++ds) {
          bf16x8 kfr = *(const bf16x8*)(Ksb + row * 64 + (((ds * 2 + hi) ^ rxk) << 3));
          S[kt] = __builtin_amdgcn_mfma_f32_32x32x16_bf16(kfr, qf[ds], S[kt], 0, 0, 0);
        }
      }
      __builtin_amdgcn_s_setprio(0);

      // ---- mask (causal on diag chunk; padding on boundary chunk)
      const bool isDiag = (i == diagI);
      if (isDiag || (kc + 64 > kmaxRaw)) {
        const int q = qw + l31;
#pragma unroll
        for (int kt = 0; kt < 2; ++kt)
#pragma unroll
          for (int rr = 0; rr < 16; ++rr) {
            int key = kc + kt * 32 + (rr & 3) + ((rr >> 2) << 3) + (hi << 2);
            if ((isDiag && key > q) || key >= kmaxRaw) S[kt][rr] = -1e30f;
          }
      }

      // ---- online softmax (q lane-local) with defer-max (THR=8)
      {
        float v[16];
#pragma unroll
        for (int rr = 0; rr < 16; ++rr) v[rr] = fmaxf(S[0][rr], S[1][rr]);
#pragma unroll
        for (int st = 8; st; st >>= 1)
#pragma unroll
          for (int rr = 0; rr < st; ++rr) v[rr] = fmaxf(v[rr], v[rr + st]);
        float mx = fmaxf(v[0], __shfl_xor(v[0], 32, 64));
        if (__any(mx > mR + 8.0f)) {
          float mnew = fmaxf(mR, mx);
          float a = __builtin_amdgcn_exp2f(mR - mnew);
          mR = mnew;
          lR *= a;
#pragma unroll
          for (int mt = 0; mt < 2; ++mt)
#pragma unroll
            for (int rr = 0; rr < 16; ++rr) O[mt][rr] *= a;
        }
#pragma unroll
        for (int kt = 0; kt < 2; ++kt)
#pragma unroll
          for (int rr = 0; rr < 16; ++rr)
            S[kt][rr] = __builtin_amdgcn_exp2f(S[kt][rr] - mR);
        float sacc[16];
#pragma unroll
        for (int rr = 0; rr < 16; ++rr) sacc[rr] = S[0][rr] + S[1][rr];
#pragma unroll
        for (int st = 8; st; st >>= 1)
#pragma unroll
          for (int rr = 0; rr < st; ++rr) sacc[rr] += sacc[rr + st];
        lR += sacc[0] + __shfl_xor(sacc[0], 32, 64);
      }
      // pack P into PV B-frags (n=q=l31, k=key=8*hi+j within 16-key step)
      bf16x8 pf[2][2];
#pragma unroll
      for (int kt = 0; kt < 2; ++kt) {
        unsigned a0 = pkbf(S[kt][0], S[kt][1]);
        unsigned a1 = pkbf(S[kt][2], S[kt][3]);
        unsigned b0 = pkbf(S[kt][4], S[kt][5]);
        unsigned b1 = pkbf(S[kt][6], S[kt][7]);
        unsigned c0 = pkbf(S[kt][8], S[kt][9]);
        unsigned c1 = pkbf(S[kt][10], S[kt][11]);
        unsigned d0 = pkbf(S[kt][12], S[kt][13]);
        unsigned d1 = pkbf(S[kt][14], S[kt][15]);
        unsigned s0 = __shfl_xor(hi ? a0 : b0, 32, 64);
        unsigned s1 = __shfl_xor(hi ? a1 : b1, 32, 64);
        unsigned s2 = __shfl_xor(hi ? c0 : d0, 32, 64);
        unsigned s3 = __shfl_xor(hi ? c1 : d1, 32, 64);
        u32x4 f0, f1;
        f0[0] = hi ? s0 : a0; f0[1] = hi ? s1 : a1;
        f0[2] = hi ? b0 : s0; f0[3] = hi ? b1 : s1;
        f1[0] = hi ? s2 : c0; f1[1] = hi ? s3 : c1;
        f1[2] = hi ? d0 : s2; f1[3] = hi ? d1 : s3;
        pf[kt][0] = __builtin_bit_cast(bf16x8, f0);
        pf[kt][1] = __builtin_bit_cast(bf16x8, f1);
      }

      // ---- PV: O^T += V^T . P   (A=V^T: m=hd, k=key; B=P)
      __builtin_amdgcn_s_setprio(1);
      const int vx = l31 & 7;
#pragma unroll
      for (int kt = 0; kt < 2; ++kt)
#pragma unroll
        for (int ks = 0; ks < 2; ++ks) {
          const int slot = kt * 4 + ks * 2 + hi;
          bf16x8 v0 = *(const bf16x8*)(Vsb + l31 * 64 + ((slot ^ vx) << 3));
          bf16x8 v1 = *(const bf16x8*)(Vsb + (32 + l31) * 64 + ((slot ^ vx) << 3));
          O[0] = __builtin_amdgcn_mfma_f32_32x32x16_bf16(v0, pf[kt][ks], O[0], 0, 0, 0);
          O[1] = __builtin_amdgcn_mfma_f32_32x32x16_bf16(v1, pf[kt][ks], O[1], 0, 0, 0);
        }
      __builtin_amdgcn_s_setprio(0);
    }
    cb = (cb == 2) ? 0 : cb + 1;
    sb = (sb == 2) ? 0 : sb + 1;
  }

  // ---- epilogue: O^T normalize, write ctx[q][h*64+hd] (q lane-local)
  {
    float linv = 1.0f / lR;
    const int q = qw + l31;
    unsigned short* cp = ctxBase + (size_t)q * 1024;
#pragma unroll
    for (int mt = 0; mt < 2; ++mt)
#pragma unroll
      for (int g = 0; g < 4; ++g) {
        u16x4 o4;
#pragma unroll
        for (int rr = 0; rr < 4; ++rr) o4[rr] = f2bf(O[mt][4 * g + rr] * linv);
        *(u16x4*)(cp + mt * 32 + 8 * g + 4 * hi) = o4;
      }
  }
}

// ---------------------------------------------------------------- launch
extern "C" void kernel_launch(void* const* d_in, const int* in_sizes, int n_in,
                              void* d_out, int out_size, void* d_ws, size_t ws_size,
                              hipStream_t stream) {
  const float* x    = (const float*)d_in[0];
  const float* Wqkv = (const float*)d_in[1];
  const float* bqkv = (const float*)d_in[2];
  const float* Wo   = (const float*)d_in[3];
  const float* bo   = (const float*)d_in[4];
  const int*   mask = (const int*)d_in[5];
  float* out = (float*)d_out;

  unsigned short* ws = (unsigned short*)d_ws;
  const size_t SZ_X = (size_t)8192 * 1024;  // B*T*D
  unsigned short* xb    = ws;                                   // 16 MB, reused as ctx
  unsigned short* WqkvT = xb + SZ_X;                            // 6 MB
  unsigned short* WoT   = WqkvT + (size_t)3072 * 1024;          // 2 MB
  unsigned short* Qb    = WoT + (size_t)1024 * 1024;            // 16 MB
  unsigned short* Kb    = Qb + SZ_X;                            // 16 MB
  unsigned short* Vt    = Kb + SZ_X;                            // 16 MB
  int*            kparts = (int*)(Vt + SZ_X);                   // 128 B
  unsigned short* ctx   = xb;  // xb dead after GEMM1

  static bool inited = false;
  if (!inited) {
    hipFuncSetAttribute((const void*)gemm_bt<0>,
                        hipFuncAttributeMaxDynamicSharedMemorySize, 147456);
    hipFuncSetAttribute((const void*)gemm_bt<1>,
                        hipFuncAttributeMaxDynamicSharedMemorySize, 147456);
    inited = true;
  }

  prep_fused<<<8224, 256, 0, stream>>>(x, xb, Wqkv, WqkvT, Wo, WoT, mask, kparts);
  gemm_bt<0><<<dim3(32, 24), 512, 147456, stream>>>(xb, WqkvT, bqkv, nullptr, Qb, Kb, Vt,
                                                    8192, 3072, 1024);
  flash_attn<<<1024, 256, 0, stream>>>(Qb, Kb, Vt, kparts, ctx);
  gemm_bt<1><<<dim3(32, 8), 512, 147456, stream>>>(ctx, WoT, bo, out, nullptr, nullptr, nullptr,
                                                   8192, 1024, 1024);
}

// Round 8
// 259.949 us; speedup vs baseline: 1.0742x; 1.0338x over previous
//
#include <hip/hip_runtime.h>
#include <cstdint>
#include <cstddef>

typedef __bf16 bf16x8 __attribute__((ext_vector_type(8)));
typedef float f32x4 __attribute__((ext_vector_type(4)));
typedef float f32x16 __attribute__((ext_vector_type(16)));
typedef unsigned short u16x4 __attribute__((ext_vector_type(4)));
typedef unsigned int u32x4 __attribute__((ext_vector_type(4)));

// fp32 -> bf16 round-to-nearest-even
__device__ __forceinline__ unsigned short f2bf(float f) {
  union { float f; unsigned u; } v; v.f = f;
  unsigned r = (v.u + 0x7FFF + ((v.u >> 16) & 1)) >> 16;
  return (unsigned short)r;
}

// pack two floats into one u32 of 2 bf16
__device__ __forceinline__ unsigned pkbf(float x, float y) {
  unsigned short a = __builtin_bit_cast(unsigned short, (__bf16)x);
  unsigned short b = __builtin_bit_cast(unsigned short, (__bf16)y);
  return (unsigned)a | ((unsigned)b << 16);
}

// async global->LDS, 16B per lane
__device__ __forceinline__ void gl2lds16(const void* g, void* l) {
  __builtin_amdgcn_global_load_lds(
      (const __attribute__((address_space(1))) void*)g,
      (__attribute__((address_space(3))) void*)l,
      16, 0, 0);
}

// ---------------------------------------------------------------- fused prep
__global__ __launch_bounds__(256) void prep_fused(
    const float* __restrict__ x, unsigned short* __restrict__ xb,
    const float* __restrict__ Wqkv, unsigned short* __restrict__ WqkvT,
    const float* __restrict__ Wo, unsigned short* __restrict__ WoT,
    const int* __restrict__ mask, int* __restrict__ kparts) {
  __shared__ float t[32][33];
  __shared__ int wred[4];
  const int bid = blockIdx.x, tid = threadIdx.x;
  if (bid < 4096) {
    // cast x -> bf16, 2 chunks of 4 floats per thread
    size_t i = ((size_t)bid * 256 + tid) * 4;
#pragma unroll
    for (int c = 0; c < 2; ++c) {
      float4 v = *(const float4*)(x + i);
      u16x4 o;
      o[0] = f2bf(v.x); o[1] = f2bf(v.y); o[2] = f2bf(v.z); o[3] = f2bf(v.w);
      *(u16x4*)(xb + i) = o;
      i += (size_t)4096 * 256 * 4;
    }
  } else if (bid < 4096 + 3072) {
    // transpose+cast Wqkv [1024,3072] -> WqkvT [3072,1024]
    const int b2 = bid - 4096;
    const int c0 = (b2 % 96) * 32, r0 = (b2 / 96) * 32;
    const int tx = tid & 31, ty = tid >> 5;
#pragma unroll
    for (int j = 0; j < 4; ++j)
      t[ty + j * 8][tx] = Wqkv[(size_t)(r0 + ty + j * 8) * 3072 + c0 + tx];
    __syncthreads();
#pragma unroll
    for (int j = 0; j < 4; ++j)
      WqkvT[(size_t)(c0 + ty + j * 8) * 1024 + r0 + tx] = f2bf(t[tx][ty + j * 8]);
  } else if (bid < 8192) {
    // transpose+cast Wo [1024,1024] -> WoT
    const int b3 = bid - (4096 + 3072);
    const int c0 = (b3 & 31) * 32, r0 = (b3 >> 5) * 32;
    const int tx = tid & 31, ty = tid >> 5;
#pragma unroll
    for (int j = 0; j < 4; ++j)
      t[ty + j * 8][tx] = Wo[(size_t)(r0 + ty + j * 8) * 1024 + c0 + tx];
    __syncthreads();
#pragma unroll
    for (int j = 0; j < 4; ++j)
      WoT[(size_t)(c0 + ty + j * 8) * 1024 + r0 + tx] = f2bf(t[tx][ty + j * 8]);
  } else {
    // per-block (256 mask entries) max unpadded key index+1 -> kparts[32]
    const int bi = bid - 8192;           // 0..31, 8 blocks per batch
    const int i = bi * 256 + tid;
    int mv = mask[i];
    int key = mv ? 0 : ((i & 2047) + 1);
#pragma unroll
    for (int off = 32; off; off >>= 1) key = max(key, __shfl_xor(key, off, 64));
    if ((tid & 63) == 0) wred[tid >> 6] = key;
    __syncthreads();
    if (tid == 0)
      kparts[bi] = max(max(wred[0], wred[1]), max(wred[2], wred[3]));
  }
}

// ---------------------------------------------------------------- GEMM (C = A[M,K] * B[N,K]^T)
// Round 8: same counted-vmcnt 3-buffer pipeline as round 5/7 (639 TF), plus
// an L2-SUPERTILE block remap: at 144KB LDS the kernel runs 1 block/CU, and
// the 4032-cy/K-step gap (vs ~310 MFMA + ~1300 LDS) points at staging feed —
// A panels were re-read 24x and B 32x from L3 (~4.9 TB/s aggregate).
// Remap (1D grid): xcd = lid&7, w = lid>>3, s = w>>5, a = w&31;
//   bm = xcd*4 + (a&3), bn = s*8 + (a>>2).
// Each XCD's 32 co-resident blocks = a 4bm x 8bn supertile: A 2MB + B 2MB =
// 4MB = one XCD's L2. A-panel stays L2-resident for the whole kernel;
// staging feeds from L2 (34.5 TB/s) instead of L3. Bijective for both grids
// (768 = 8x3x32, 256 = 8x1x32). Worst case: neutral (index math only).
template <int EPI>
__global__ __launch_bounds__(512, 2) void gemm_bt(
    const unsigned short* __restrict__ A, const unsigned short* __restrict__ Bm,
    const float* __restrict__ bias, float* __restrict__ outF,
    unsigned short* __restrict__ Qb, unsigned short* __restrict__ Kb,
    unsigned short* __restrict__ Vt, int M, int N, int K) {
  extern __shared__ unsigned short lds[];  // 3 bufs x (A 16384 + B 8192) els
  const int tid = threadIdx.x;
  const int lid = blockIdx.x;
  const int xcd = lid & 7, w = lid >> 3;
  const int s = w >> 5, a = w & 31;
  const int bm = (xcd * 4 + (a & 3)) << 8;   // * 256
  const int bn = (s * 8 + (a >> 2)) << 7;    // * 128
  const int wave = tid >> 6, lane = tid & 63;
  const int wm4 = wave >> 1, wn2 = wave & 1;   // 4 m-waves x 2 n-waves
  const int lr = lane & 15, lq = lane >> 4;
  const int NT = K >> 6;

  f32x4 acc[4][4] = {};

  const int tr = tid >> 3, ts = tid & 7;
  const int srcsl = (ts ^ (tr & 7)) << 3;      // pre-swizzled col slot (els)

  auto stage = [&](int buf, int k0) {
#pragma unroll
    for (int r = 0; r < 4; ++r)
      gl2lds16(A + (size_t)(bm + r * 64 + tr) * K + k0 + srcsl,
               lds + buf * 24576 + r * 4096 + tid * 8);
#pragma unroll
    for (int r = 0; r < 2; ++r)
      gl2lds16(Bm + (size_t)(bn + r * 64 + tr) * K + k0 + srcsl,
               lds + buf * 24576 + 16384 + r * 4096 + tid * 8);
  };

  stage(0, 0);
  stage(1, 64);
  int bT = 0, bT2 = 2;
  const int rx = lr & 7;  // read-side swizzle key (row&7 == lr&7 here)
  for (int T = 0; T < NT; ++T) {
    if (T < NT - 1) {
      asm volatile("s_waitcnt vmcnt(6)" ::: "memory");
    } else {
      asm volatile("s_waitcnt vmcnt(0)" ::: "memory");
    }
    __builtin_amdgcn_s_barrier();
    __builtin_amdgcn_sched_barrier(0);
    if (T + 2 < NT) stage(bT2, (T + 2) << 6);
    const unsigned short* Ab = lds + bT * 24576;
    const unsigned short* Bb = Ab + 16384;
#pragma unroll
    for (int ks = 0; ks < 2; ++ks) {
      bf16x8 afr[4], bfr[4];
#pragma unroll
      for (int mi = 0; mi < 4; ++mi) {
        int row = wm4 * 64 + mi * 16 + lr;
        afr[mi] = *(const bf16x8*)(Ab + row * 64 + ((((ks << 2) | lq) ^ rx) << 3));
      }
#pragma unroll
      for (int nj = 0; nj < 4; ++nj) {
        int row = wn2 * 64 + nj * 16 + lr;
        bfr[nj] = *(const bf16x8*)(Bb + row * 64 + ((((ks << 2) | lq) ^ rx) << 3));
      }
      __builtin_amdgcn_s_setprio(1);
#pragma unroll
      for (int mi = 0; mi < 4; ++mi)
#pragma unroll
        for (int nj = 0; nj < 4; ++nj)
          acc[mi][nj] = __builtin_amdgcn_mfma_f32_16x16x32_bf16(afr[mi], bfr[nj], acc[mi][nj], 0, 0, 0);
      __builtin_amdgcn_s_setprio(0);
    }
    bT = (bT == 2) ? 0 : bT + 1;
    bT2 = (bT2 == 2) ? 0 : bT2 + 1;
  }

#pragma unroll
  for (int mi = 0; mi < 4; ++mi) {
#pragma unroll
    for (int nj = 0; nj < 4; ++nj) {
#pragma unroll
      for (int r = 0; r < 4; ++r) {
        int m = bm + wm4 * 64 + mi * 16 + lq * 4 + r;
        int n = bn + wn2 * 64 + nj * 16 + lr;
        float v = acc[mi][nj][r] + bias[n];
        if (EPI == 0) {
          int b = m >> 11, t = m & 2047;
          int part = n >> 10, d = n & 1023;
          int h = d >> 6, hd = d & 63;
          size_t qk = ((size_t)(b * 16 + h) * 2048 + t) * 64 + hd;
          // fold softmax scale 1/sqrt(64) and log2(e) into Q
          if (part == 0)      Qb[qk] = f2bf(v * 0.18033688011112042f);
          else if (part == 1) Kb[qk] = f2bf(v);
          else                Vt[((size_t)(b * 16 + h) * 64 + hd) * 2048 + t] = f2bf(v);
        } else {
          outF[(size_t)m * N + n] = v;
        }
      }
    }
  }
}

// ---------------------------------------------------------------- flash attention
// Round 8: revert to the round-5 proven loop shape — 2 LDS buffers (32KB,
// 4 blocks/CU) + __syncthreads per chunk. Round-7's 3-buffer/48KB counted
// vmcnt cost a resident block (4->3) and net-regressed ~9us: with
// stage-after-barrier, chunk i's loads get a full compute phase of cover, so
// the drain was nearly free. Kept from r7: kparts reduce, defer-max (THR=8).
// New: max-reduce written as fmaxf(fmaxf(x,y),z) triples -> v_max3_f32
// (31 -> 16 ops on the VALU-heavy softmax path; VALUBusy was 53%).
__global__ __launch_bounds__(256, 4) void flash_attn(
    const unsigned short* __restrict__ Qb, const unsigned short* __restrict__ Kb,
    const unsigned short* __restrict__ Vt, const int* __restrict__ kparts,
    unsigned short* __restrict__ ctx) {
  __shared__ unsigned short lds[16384];  // 2 bufs x [ K 4096 | V 4096 ] els

  const int bid = blockIdx.x;            // 1024 blocks
  const int halfg = bid >> 9;            // 0/1
  const int rb = bid & 511;
  const int bh = rb & 63;                // bid%8 == bh%8 -> XCD locality
  const int j0 = rb >> 6;                // 0..7
  const int j = halfg ? (15 - j0) : j0;  // q-superblock 0..15, paired for balance
  const int blockQ = j << 7;             // 128 q-rows per block
  const int b = bh >> 4, h = bh & 15;
  const int tid = threadIdx.x;
  const int wave = tid >> 6, lane = tid & 63;
  const int l31 = lane & 31, hi = lane >> 5;
  const int qw = blockQ + wave * 32;     // wave's 32 q-rows

  const unsigned short* Qh = Qb + (size_t)bh * 2048 * 64;
  const unsigned short* Kh = Kb + (size_t)bh * 2048 * 64;
  const unsigned short* Vh = Vt + (size_t)bh * 64 * 2048;
  unsigned short* ctxBase = ctx + (size_t)b * 2048 * 1024 + h * 64;

  int kmaxRaw = 0;
#pragma unroll
  for (int p = 0; p < 8; ++p) kmaxRaw = max(kmaxRaw, kparts[b * 8 + p]);
  const int kcapC = (kmaxRaw + 63) >> 6;
  const int lastB = min((blockQ + 127) >> 6, kcapC - 1);
  const int diagI = qw >> 6;

  bf16x8 qf[4];
#pragma unroll
  for (int ds = 0; ds < 4; ++ds)
    qf[ds] = *(const bf16x8*)(Qh + (size_t)(qw + l31) * 64 + ds * 16 + hi * 8);

  f32x16 O[2] = {};
  float mR = -1e30f, lR = 0.f;

  const int trow = tid >> 3, tslot = tid & 7;

  auto stage = [&](int bufI, int kcS) {
#pragma unroll
    for (int rnd = 0; rnd < 2; ++rnd) {
      int row = rnd * 32 + trow;
      int sl = tslot ^ (row & 7);
      gl2lds16(Kh + (size_t)(kcS + row) * 64 + sl * 8,
               lds + bufI * 8192 + rnd * 2048 + tid * 8);
      gl2lds16(Vh + (size_t)row * 2048 + kcS + sl * 8,
               lds + bufI * 8192 + 4096 + rnd * 2048 + tid * 8);
    }
  };

  stage(0, 0);
  int cur = 0;
  for (int i = 0; i <= lastB; ++i) {
    __syncthreads();  // buf[cur] staged; prior reads of buf[cur^1] done
    if (i < lastB) stage(cur ^ 1, (i + 1) << 6);
    if (i <= diagI) {
      const int kc = i << 6;
      const unsigned short* Ksb = lds + cur * 8192;
      const unsigned short* Vsb = Ksb + 4096;

      // ---- QK^T: S^T[key][q], A=K (m=key), B=Q^T (n=q)
      f32x16 S[2] = {};
      __builtin_amdgcn_s_setprio(1);
#pragma unroll
      for (int kt = 0; kt < 2; ++kt) {
        const int row = kt * 32 + l31;
        const int rxk = row & 7;
#pragma unroll
        for (int ds = 0; ds < 4; ++ds) {
          bf16x8 kfr = *(const bf16x8*)(Ksb + row * 64 + (((ds * 2 + hi) ^ rxk) << 3));
          S[kt] = __builtin_amdgcn_mfma_f32_32x32x16_bf16(kfr, qf[ds], S[kt], 0, 0, 0);
        }
      }
      __builtin_amdgcn_s_setprio(0);

      // ---- mask (causal on diag chunk; padding on boundary chunk)
      const bool isDiag = (i == diagI);
      if (isDiag || (kc + 64 > kmaxRaw)) {
        const int q = qw + l31;
#pragma unroll
        for (int kt = 0; kt < 2; ++kt)
#pragma unroll
          for (int rr = 0; rr < 16; ++rr) {
            int key = kc + kt * 32 + (rr & 3) + ((rr >> 2) << 3) + (hi << 2);
            if ((isDiag && key > q) || key >= kmaxRaw) S[kt][rr] = -1e30f;
          }
      }

      // ---- online softmax (q lane-local) with defer-max (THR=8), max3 tree
      {
        float a8[8];
#pragma unroll
        for (int r = 0; r < 8; ++r)
          a8[r] = fmaxf(fmaxf(S[0][r], S[0][r + 8]), S[1][r]);
        float b4[4];
#pragma unroll
        for (int r = 0; r < 4; ++r)
          b4[r] = fmaxf(fmaxf(a8[r], a8[r + 4]), S[1][r + 8]);
        float c0 = fmaxf(fmaxf(b4[0], b4[2]), S[1][12]);
        float c1 = fmaxf(fmaxf(b4[1], b4[3]), S[1][13]);
        float d = fmaxf(fmaxf(c0, c1), S[1][14]);
        float mxl = fmaxf(d, S[1][15]);
        float mx = fmaxf(mxl, __shfl_xor(mxl, 32, 64));
        if (__any(mx > mR + 8.0f)) {
          float mnew = fmaxf(mR, mx);
          float aa = __builtin_amdgcn_exp2f(mR - mnew);
          mR = mnew;
          lR *= aa;
#pragma unroll
          for (int mt = 0; mt < 2; ++mt)
#pragma unroll
            for (int rr = 0; rr < 16; ++rr) O[mt][rr] *= aa;
        }
#pragma unroll
        for (int kt = 0; kt < 2; ++kt)
#pragma unroll
          for (int rr = 0; rr < 16; ++rr)
            S[kt][rr] = __builtin_amdgcn_exp2f(S[kt][rr] - mR);
        float sacc[16];
#pragma unroll
        for (int rr = 0; rr < 16; ++rr) sacc[rr] = S[0][rr] + S[1][rr];
#pragma unroll
        for (int st = 8; st; st >>= 1)
#pragma unroll
          for (int rr = 0; rr < st; ++rr) sacc[rr] += sacc[rr + st];
        lR += sacc[0] + __shfl_xor(sacc[0], 32, 64);
      }
      // pack P into PV B-frags (n=q=l31, k=key=8*hi+j within 16-key step)
      bf16x8 pf[2][2];
#pragma unroll
      for (int kt = 0; kt < 2; ++kt) {
        unsigned a0 = pkbf(S[kt][0], S[kt][1]);
        unsigned a1 = pkbf(S[kt][2], S[kt][3]);
        unsigned b0 = pkbf(S[kt][4], S[kt][5]);
        unsigned b1 = pkbf(S[kt][6], S[kt][7]);
        unsigned c0 = pkbf(S[kt][8], S[kt][9]);
        unsigned c1 = pkbf(S[kt][10], S[kt][11]);
        unsigned d0 = pkbf(S[kt][12], S[kt][13]);
        unsigned d1 = pkbf(S[kt][14], S[kt][15]);
        unsigned s0 = __shfl_xor(hi ? a0 : b0, 32, 64);
        unsigned s1 = __shfl_xor(hi ? a1 : b1, 32, 64);
        unsigned s2 = __shfl_xor(hi ? c0 : d0, 32, 64);
        unsigned s3 = __shfl_xor(hi ? c1 : d1, 32, 64);
        u32x4 f0, f1;
        f0[0] = hi ? s0 : a0; f0[1] = hi ? s1 : a1;
        f0[2] = hi ? b0 : s0; f0[3] = hi ? b1 : s1;
        f1[0] = hi ? s2 : c0; f1[1] = hi ? s3 : c1;
        f1[2] = hi ? d0 : s2; f1[3] = hi ? d1 : s3;
        pf[kt][0] = __builtin_bit_cast(bf16x8, f0);
        pf[kt][1] = __builtin_bit_cast(bf16x8, f1);
      }

      // ---- PV: O^T += V^T . P   (A=V^T: m=hd, k=key; B=P)
      __builtin_amdgcn_s_setprio(1);
      const int vx = l31 & 7;
#pragma unroll
      for (int kt = 0; kt < 2; ++kt)
#pragma unroll
        for (int ks = 0; ks < 2; ++ks) {
          const int slot = kt * 4 + ks * 2 + hi;
          bf16x8 v0 = *(const bf16x8*)(Vsb + l31 * 64 + ((slot ^ vx) << 3));
          bf16x8 v1 = *(const bf16x8*)(Vsb + (32 + l31) * 64 + ((slot ^ vx) << 3));
          O[0] = __builtin_amdgcn_mfma_f32_32x32x16_bf16(v0, pf[kt][ks], O[0], 0, 0, 0);
          O[1] = __builtin_amdgcn_mfma_f32_32x32x16_bf16(v1, pf[kt][ks], O[1], 0, 0, 0);
        }
      __builtin_amdgcn_s_setprio(0);
    }
    cur ^= 1;
  }

  // ---- epilogue: O^T normalize, write ctx[q][h*64+hd] (q lane-local)
  {
    float linv = 1.0f / lR;
    const int q = qw + l31;
    unsigned short* cp = ctxBase + (size_t)q * 1024;
#pragma unroll
    for (int mt = 0; mt < 2; ++mt)
#pragma unroll
      for (int g = 0; g < 4; ++g) {
        u16x4 o4;
#pragma unroll
        for (int rr = 0; rr < 4; ++rr) o4[rr] = f2bf(O[mt][4 * g + rr] * linv);
        *(u16x4*)(cp + mt * 32 + 8 * g + 4 * hi) = o4;
      }
  }
}

// ---------------------------------------------------------------- launch
extern "C" void kernel_launch(void* const* d_in, const int* in_sizes, int n_in,
                              void* d_out, int out_size, void* d_ws, size_t ws_size,
                              hipStream_t stream) {
  const float* x    = (const float*)d_in[0];
  const float* Wqkv = (const float*)d_in[1];
  const float* bqkv = (const float*)d_in[2];
  const float* Wo   = (const float*)d_in[3];
  const float* bo   = (const float*)d_in[4];
  const int*   mask = (const int*)d_in[5];
  float* out = (float*)d_out;

  unsigned short* ws = (unsigned short*)d_ws;
  const size_t SZ_X = (size_t)8192 * 1024;  // B*T*D
  unsigned short* xb    = ws;                                   // 16 MB, reused as ctx
  unsigned short* WqkvT = xb + SZ_X;                            // 6 MB
  unsigned short* WoT   = WqkvT + (size_t)3072 * 1024;          // 2 MB
  unsigned short* Qb    = WoT + (size_t)1024 * 1024;            // 16 MB
  unsigned short* Kb    = Qb + SZ_X;                            // 16 MB
  unsigned short* Vt    = Kb + SZ_X;                            // 16 MB
  int*            kparts = (int*)(Vt + SZ_X);                   // 128 B
  unsigned short* ctx   = xb;  // xb dead after GEMM1

  static bool inited = false;
  if (!inited) {
    hipFuncSetAttribute((const void*)gemm_bt<0>,
                        hipFuncAttributeMaxDynamicSharedMemorySize, 147456);
    hipFuncSetAttribute((const void*)gemm_bt<1>,
                        hipFuncAttributeMaxDynamicSharedMemorySize, 147456);
    inited = true;
  }

  prep_fused<<<8224, 256, 0, stream>>>(x, xb, Wqkv, WqkvT, Wo, WoT, mask, kparts);
  gemm_bt<0><<<768, 512, 147456, stream>>>(xb, WqkvT, bqkv, nullptr, Qb, Kb, Vt,
                                           8192, 3072, 1024);
  flash_attn<<<1024, 256, 0, stream>>>(Qb, Kb, Vt, kparts, ctx);
  gemm_bt<1><<<256, 512, 147456, stream>>>(ctx, WoT, bo, out, nullptr, nullptr, nullptr,
                                           8192, 1024, 1024);
}

// Round 12
// 249.968 us; speedup vs baseline: 1.1171x; 1.0399x over previous
//
#include <hip/hip_runtime.h>
#include <cstdint>
#include <cstddef>

typedef __bf16 bf16x8 __attribute__((ext_vector_type(8)));
typedef float f32x4 __attribute__((ext_vector_type(4)));
typedef float f32x16 __attribute__((ext_vector_type(16)));
typedef unsigned short u16x4 __attribute__((ext_vector_type(4)));
typedef unsigned int u32x4 __attribute__((ext_vector_type(4)));

// fp32 -> bf16 round-to-nearest-even
__device__ __forceinline__ unsigned short f2bf(float f) {
  union { float f; unsigned u; } v; v.f = f;
  unsigned r = (v.u + 0x7FFF + ((v.u >> 16) & 1)) >> 16;
  return (unsigned short)r;
}

// pack two floats into one u32 of 2 bf16
__device__ __forceinline__ unsigned pkbf(float x, float y) {
  unsigned short a = __builtin_bit_cast(unsigned short, (__bf16)x);
  unsigned short b = __builtin_bit_cast(unsigned short, (__bf16)y);
  return (unsigned)a | ((unsigned)b << 16);
}

// async global->LDS, 16B per lane
__device__ __forceinline__ void gl2lds16(const void* g, void* l) {
  __builtin_amdgcn_global_load_lds(
      (const __attribute__((address_space(1))) void*)g,
      (__attribute__((address_space(3))) void*)l,
      16, 0, 0);
}

// ---------------------------------------------------------------- fused prep
__global__ __launch_bounds__(256) void prep_fused(
    const float* __restrict__ x, unsigned short* __restrict__ xb,
    const float* __restrict__ Wqkv, unsigned short* __restrict__ WqkvT,
    const float* __restrict__ Wo, unsigned short* __restrict__ WoT,
    const int* __restrict__ mask, int* __restrict__ kparts) {
  __shared__ float t[32][33];
  __shared__ int wred[4];
  const int bid = blockIdx.x, tid = threadIdx.x;
  if (bid < 4096) {
    // cast x -> bf16, 2 chunks of 4 floats per thread
    size_t i = ((size_t)bid * 256 + tid) * 4;
#pragma unroll
    for (int c = 0; c < 2; ++c) {
      float4 v = *(const float4*)(x + i);
      u16x4 o;
      o[0] = f2bf(v.x); o[1] = f2bf(v.y); o[2] = f2bf(v.z); o[3] = f2bf(v.w);
      *(u16x4*)(xb + i) = o;
      i += (size_t)4096 * 256 * 4;
    }
  } else if (bid < 4096 + 3072) {
    // transpose+cast Wqkv [1024,3072] -> WqkvT [3072,1024]
    const int b2 = bid - 4096;
    const int c0 = (b2 % 96) * 32, r0 = (b2 / 96) * 32;
    const int tx = tid & 31, ty = tid >> 5;
#pragma unroll
    for (int j = 0; j < 4; ++j)
      t[ty + j * 8][tx] = Wqkv[(size_t)(r0 + ty + j * 8) * 3072 + c0 + tx];
    __syncthreads();
#pragma unroll
    for (int j = 0; j < 4; ++j)
      WqkvT[(size_t)(c0 + ty + j * 8) * 1024 + r0 + tx] = f2bf(t[tx][ty + j * 8]);
  } else if (bid < 8192) {
    // transpose+cast Wo [1024,1024] -> WoT
    const int b3 = bid - (4096 + 3072);
    const int c0 = (b3 & 31) * 32, r0 = (b3 >> 5) * 32;
    const int tx = tid & 31, ty = tid >> 5;
#pragma unroll
    for (int j = 0; j < 4; ++j)
      t[ty + j * 8][tx] = Wo[(size_t)(r0 + ty + j * 8) * 1024 + c0 + tx];
    __syncthreads();
#pragma unroll
    for (int j = 0; j < 4; ++j)
      WoT[(size_t)(c0 + ty + j * 8) * 1024 + r0 + tx] = f2bf(t[tx][ty + j * 8]);
  } else {
    // per-block (256 mask entries) max unpadded key index+1 -> kparts[32]
    const int bi = bid - 8192;           // 0..31, 8 blocks per batch
    const int i = bi * 256 + tid;
    int mv = mask[i];
    int key = mv ? 0 : ((i & 2047) + 1);
#pragma unroll
    for (int off = 32; off; off >>= 1) key = max(key, __shfl_xor(key, off, 64));
    if ((tid & 63) == 0) wred[tid >> 6] = key;
    __syncthreads();
    if (tid == 0)
      kparts[bi] = max(max(wred[0], wred[1]), max(wred[2], wred[3]));
  }
}

// ---------------------------------------------------------------- GEMM (C = A[M,K] * B[N,K]^T)
// r5/r8 proven pipeline (counted vmcnt(6), 3 buffers, 639 TF) + dead-tile
// skip (THE ONLY delta vs the green r8 build — single-variable attribution):
// for EPI==0, bm tiles fully inside a batch's padded tail (bm%2048==1792
// when kmax<=1792) with bn in the K/V parts (bn>=1024) produce outputs flash
// never reads (it stages only keys < ceil(kmax/64)*64 <= 1792 in both Kb
// rows and Vt columns). 64 of 768 blocks exit at entry.
template <int EPI>
__global__ __launch_bounds__(512, 2) void gemm_bt(
    const unsigned short* __restrict__ A, const unsigned short* __restrict__ Bm,
    const float* __restrict__ bias, float* __restrict__ outF,
    unsigned short* __restrict__ Qb, unsigned short* __restrict__ Kb,
    unsigned short* __restrict__ Vt, const int* __restrict__ kparts,
    int M, int N, int K) {
  extern __shared__ unsigned short lds[];  // 3 bufs x (A 16384 + B 8192) els
  const int tid = threadIdx.x;
  const int lid = blockIdx.x;
  const int xcd = lid & 7, w = lid >> 3;
  const int s = w >> 5, a = w & 31;
  const int bm = (xcd * 4 + (a & 3)) << 8;   // * 256
  const int bn = (s * 8 + (a >> 2)) << 7;    // * 128
  if (EPI == 0 && bn >= 1024 && (bm & 2047) == 1792) {
    const int bb = bm >> 11;
    int km = 0;
#pragma unroll
    for (int p = 0; p < 8; ++p) km = max(km, kparts[bb * 8 + p]);
    if (km <= 1792) return;  // K/V rows for t>=1792 never read by flash
  }
  const int wave = tid >> 6, lane = tid & 63;
  const int wm4 = wave >> 1, wn2 = wave & 1;   // 4 m-waves x 2 n-waves
  const int lr = lane & 15, lq = lane >> 4;
  const int NT = K >> 6;

  f32x4 acc[4][4] = {};

  const int tr = tid >> 3, ts = tid & 7;
  const int srcsl = (ts ^ (tr & 7)) << 3;      // pre-swizzled col slot (els)

  auto stage = [&](int buf, int k0) {
#pragma unroll
    for (int r = 0; r < 4; ++r)
      gl2lds16(A + (size_t)(bm + r * 64 + tr) * K + k0 + srcsl,
               lds + buf * 24576 + r * 4096 + tid * 8);
#pragma unroll
    for (int r = 0; r < 2; ++r)
      gl2lds16(Bm + (size_t)(bn + r * 64 + tr) * K + k0 + srcsl,
               lds + buf * 24576 + 16384 + r * 4096 + tid * 8);
  };

  stage(0, 0);
  stage(1, 64);
  int bT = 0, bT2 = 2;
  const int rx = lr & 7;  // read-side swizzle key (row&7 == lr&7 here)
  for (int T = 0; T < NT; ++T) {
    if (T < NT - 1) {
      asm volatile("s_waitcnt vmcnt(6)" ::: "memory");
    } else {
      asm volatile("s_waitcnt vmcnt(0)" ::: "memory");
    }
    __builtin_amdgcn_s_barrier();
    __builtin_amdgcn_sched_barrier(0);
    if (T + 2 < NT) stage(bT2, (T + 2) << 6);
    const unsigned short* Ab = lds + bT * 24576;
    const unsigned short* Bb = Ab + 16384;
#pragma unroll
    for (int ks = 0; ks < 2; ++ks) {
      bf16x8 afr[4], bfr[4];
#pragma unroll
      for (int mi = 0; mi < 4; ++mi) {
        int row = wm4 * 64 + mi * 16 + lr;
        afr[mi] = *(const bf16x8*)(Ab + row * 64 + ((((ks << 2) | lq) ^ rx) << 3));
      }
#pragma unroll
      for (int nj = 0; nj < 4; ++nj) {
        int row = wn2 * 64 + nj * 16 + lr;
        bfr[nj] = *(const bf16x8*)(Bb + row * 64 + ((((ks << 2) | lq) ^ rx) << 3));
      }
      __builtin_amdgcn_s_setprio(1);
#pragma unroll
      for (int mi = 0; mi < 4; ++mi)
#pragma unroll
        for (int nj = 0; nj < 4; ++nj)
          acc[mi][nj] = __builtin_amdgcn_mfma_f32_16x16x32_bf16(afr[mi], bfr[nj], acc[mi][nj], 0, 0, 0);
      __builtin_amdgcn_s_setprio(0);
    }
    bT = (bT == 2) ? 0 : bT + 1;
    bT2 = (bT2 == 2) ? 0 : bT2 + 1;
  }

#pragma unroll
  for (int mi = 0; mi < 4; ++mi) {
#pragma unroll
    for (int nj = 0; nj < 4; ++nj) {
#pragma unroll
      for (int r = 0; r < 4; ++r) {
        int m = bm + wm4 * 64 + mi * 16 + lq * 4 + r;
        int n = bn + wn2 * 64 + nj * 16 + lr;
        float v = acc[mi][nj][r] + bias[n];
        if (EPI == 0) {
          int b = m >> 11, t = m & 2047;
          int part = n >> 10, d = n & 1023;
          int h = d >> 6, hd = d & 63;
          size_t qk = ((size_t)(b * 16 + h) * 2048 + t) * 64 + hd;
          // fold softmax scale 1/sqrt(64) and log2(e) into Q
          if (part == 0)      Qb[qk] = f2bf(v * 0.18033688011112042f);
          else if (part == 1) Kb[qk] = f2bf(v);
          else                Vt[((size_t)(b * 16 + h) * 64 + hd) * 2048 + t] = f2bf(v);
        } else {
          outF[(size_t)m * N + n] = v;
        }
      }
    }
  }
}

// ---------------------------------------------------------------- flash attention
// Round 12: EXACT revert to the round-8 flash (proven green at 259.9us):
// 2-buffer/32KB LDS, 4 blocks/CU, __syncthreads per chunk, row&7 swizzle,
// defer-max (THR=8), max3 tree, shfl_xor cross-lane. The permlane32_swap
// experiments (r9-r11, three different failing conventions) are shelved:
// its return convention is not determinable without finer-grained feedback
// and its EV (<10us) doesn't justify a 4th red round.
__global__ __launch_bounds__(256, 4) void flash_attn(
    const unsigned short* __restrict__ Qb, const unsigned short* __restrict__ Kb,
    const unsigned short* __restrict__ Vt, const int* __restrict__ kparts,
    unsigned short* __restrict__ ctx) {
  __shared__ unsigned short lds[16384];  // 2 bufs x [ K 4096 | V 4096 ] els

  const int bid = blockIdx.x;            // 1024 blocks
  const int halfg = bid >> 9;            // 0/1
  const int rb = bid & 511;
  const int bh = rb & 63;                // bid%8 == bh%8 -> XCD locality
  const int j0 = rb >> 6;                // 0..7
  const int j = halfg ? (15 - j0) : j0;  // q-superblock 0..15, paired for balance
  const int blockQ = j << 7;             // 128 q-rows per block
  const int b = bh >> 4, h = bh & 15;
  const int tid = threadIdx.x;
  const int wave = tid >> 6, lane = tid & 63;
  const int l31 = lane & 31, hi = lane >> 5;
  const int qw = blockQ + wave * 32;     // wave's 32 q-rows

  const unsigned short* Qh = Qb + (size_t)bh * 2048 * 64;
  const unsigned short* Kh = Kb + (size_t)bh * 2048 * 64;
  const unsigned short* Vh = Vt + (size_t)bh * 64 * 2048;
  unsigned short* ctxBase = ctx + (size_t)b * 2048 * 1024 + h * 64;

  int kmaxRaw = 0;
#pragma unroll
  for (int p = 0; p < 8; ++p) kmaxRaw = max(kmaxRaw, kparts[b * 8 + p]);
  const int kcapC = (kmaxRaw + 63) >> 6;
  const int lastB = min((blockQ + 127) >> 6, kcapC - 1);
  const int diagI = qw >> 6;

  bf16x8 qf[4];
#pragma unroll
  for (int ds = 0; ds < 4; ++ds)
    qf[ds] = *(const bf16x8*)(Qh + (size_t)(qw + l31) * 64 + ds * 16 + hi * 8);

  f32x16 O[2] = {};
  float mR = -1e30f, lR = 0.f;

  const int trow = tid >> 3, tslot = tid & 7;

  auto stage = [&](int bufI, int kcS) {
#pragma unroll
    for (int rnd = 0; rnd < 2; ++rnd) {
      int row = rnd * 32 + trow;
      int sl = tslot ^ (row & 7);
      gl2lds16(Kh + (size_t)(kcS + row) * 64 + sl * 8,
               lds + bufI * 8192 + rnd * 2048 + tid * 8);
      gl2lds16(Vh + (size_t)row * 2048 + kcS + sl * 8,
               lds + bufI * 8192 + 4096 + rnd * 2048 + tid * 8);
    }
  };

  stage(0, 0);
  int cur = 0;
  for (int i = 0; i <= lastB; ++i) {
    __syncthreads();  // buf[cur] staged; prior reads of buf[cur^1] done
    if (i < lastB) stage(cur ^ 1, (i + 1) << 6);
    if (i <= diagI) {
      const int kc = i << 6;
      const unsigned short* Ksb = lds + cur * 8192;
      const unsigned short* Vsb = Ksb + 4096;

      // ---- QK^T: S^T[key][q], A=K (m=key), B=Q^T (n=q)
      f32x16 S[2] = {};
      __builtin_amdgcn_s_setprio(1);
#pragma unroll
      for (int kt = 0; kt < 2; ++kt) {
        const int row = kt * 32 + l31;
        const int rxk = row & 7;
#pragma unroll
        for (int ds = 0; ds < 4; ++ds) {
          bf16x8 kfr = *(const bf16x8*)(Ksb + row * 64 + (((ds * 2 + hi) ^ rxk) << 3));
          S[kt] = __builtin_amdgcn_mfma_f32_32x32x16_bf16(kfr, qf[ds], S[kt], 0, 0, 0);
        }
      }
      __builtin_amdgcn_s_setprio(0);

      // ---- mask (causal on diag chunk; padding on boundary chunk)
      const bool isDiag = (i == diagI);
      if (isDiag || (kc + 64 > kmaxRaw)) {
        const int q = qw + l31;
#pragma unroll
        for (int kt = 0; kt < 2; ++kt)
#pragma unroll
          for (int rr = 0; rr < 16; ++rr) {
            int key = kc + kt * 32 + (rr & 3) + ((rr >> 2) << 3) + (hi << 2);
            if ((isDiag && key > q) || key >= kmaxRaw) S[kt][rr] = -1e30f;
          }
      }

      // ---- online softmax (q lane-local) with defer-max (THR=8), max3 tree
      {
        float a8[8];
#pragma unroll
        for (int r = 0; r < 8; ++r)
          a8[r] = fmaxf(fmaxf(S[0][r], S[0][r + 8]), S[1][r]);
        float b4[4];
#pragma unroll
        for (int r = 0; r < 4; ++r)
          b4[r] = fmaxf(fmaxf(a8[r], a8[r + 4]), S[1][r + 8]);
        float c0 = fmaxf(fmaxf(b4[0], b4[2]), S[1][12]);
        float c1 = fmaxf(fmaxf(b4[1], b4[3]), S[1][13]);
        float d = fmaxf(fmaxf(c0, c1), S[1][14]);
        float mxl = fmaxf(d, S[1][15]);
        float mx = fmaxf(mxl, __shfl_xor(mxl, 32, 64));
        if (__any(mx > mR + 8.0f)) {
          float mnew = fmaxf(mR, mx);
          float aa = __builtin_amdgcn_exp2f(mR - mnew);
          mR = mnew;
          lR *= aa;
#pragma unroll
          for (int mt = 0; mt < 2; ++mt)
#pragma unroll
            for (int rr = 0; rr < 16; ++rr) O[mt][rr] *= aa;
        }
#pragma unroll
        for (int kt = 0; kt < 2; ++kt)
#pragma unroll
          for (int rr = 0; rr < 16; ++rr)
            S[kt][rr] = __builtin_amdgcn_exp2f(S[kt][rr] - mR);
        float sacc[16];
#pragma unroll
        for (int rr = 0; rr < 16; ++rr) sacc[rr] = S[0][rr] + S[1][rr];
#pragma unroll
        for (int st = 8; st; st >>= 1)
#pragma unroll
          for (int rr = 0; rr < st; ++rr) sacc[rr] += sacc[rr + st];
        lR += sacc[0] + __shfl_xor(sacc[0], 32, 64);
      }
      // pack P into PV B-frags (n=q=l31, k=key=8*hi+j within 16-key step)
      bf16x8 pf[2][2];
#pragma unroll
      for (int kt = 0; kt < 2; ++kt) {
        unsigned a0 = pkbf(S[kt][0], S[kt][1]);
        unsigned a1 = pkbf(S[kt][2], S[kt][3]);
        unsigned b0 = pkbf(S[kt][4], S[kt][5]);
        unsigned b1 = pkbf(S[kt][6], S[kt][7]);
        unsigned c0 = pkbf(S[kt][8], S[kt][9]);
        unsigned c1 = pkbf(S[kt][10], S[kt][11]);
        unsigned d0 = pkbf(S[kt][12], S[kt][13]);
        unsigned d1 = pkbf(S[kt][14], S[kt][15]);
        unsigned s0 = __shfl_xor(hi ? a0 : b0, 32, 64);
        unsigned s1 = __shfl_xor(hi ? a1 : b1, 32, 64);
        unsigned s2 = __shfl_xor(hi ? c0 : d0, 32, 64);
        unsigned s3 = __shfl_xor(hi ? c1 : d1, 32, 64);
        u32x4 f0, f1;
        f0[0] = hi ? s0 : a0; f0[1] = hi ? s1 : a1;
        f0[2] = hi ? b0 : s0; f0[3] = hi ? b1 : s1;
        f1[0] = hi ? s2 : c0; f1[1] = hi ? s3 : c1;
        f1[2] = hi ? d0 : s2; f1[3] = hi ? d1 : s3;
        pf[kt][0] = __builtin_bit_cast(bf16x8, f0);
        pf[kt][1] = __builtin_bit_cast(bf16x8, f1);
      }

      // ---- PV: O^T += V^T . P   (A=V^T: m=hd, k=key; B=P)
      __builtin_amdgcn_s_setprio(1);
      const int vx = l31 & 7;  // == (32+l31)&7
#pragma unroll
      for (int kt = 0; kt < 2; ++kt)
#pragma unroll
        for (int ks = 0; ks < 2; ++ks) {
          const int slot = kt * 4 + ks * 2 + hi;
          bf16x8 v0 = *(const bf16x8*)(Vsb + l31 * 64 + ((slot ^ vx) << 3));
          bf16x8 v1 = *(const bf16x8*)(Vsb + (32 + l31) * 64 + ((slot ^ vx) << 3));
          O[0] = __builtin_amdgcn_mfma_f32_32x32x16_bf16(v0, pf[kt][ks], O[0], 0, 0, 0);
          O[1] = __builtin_amdgcn_mfma_f32_32x32x16_bf16(v1, pf[kt][ks], O[1], 0, 0, 0);
        }
      __builtin_amdgcn_s_setprio(0);
    }
    cur ^= 1;
  }

  // ---- epilogue: O^T normalize, write ctx[q][h*64+hd] (q lane-local)
  {
    float linv = 1.0f / lR;
    const int q = qw + l31;
    unsigned short* cp = ctxBase + (size_t)q * 1024;
#pragma unroll
    for (int mt = 0; mt < 2; ++mt)
#pragma unroll
      for (int g = 0; g < 4; ++g) {
        u16x4 o4;
#pragma unroll
        for (int rr = 0; rr < 4; ++rr) o4[rr] = f2bf(O[mt][4 * g + rr] * linv);
        *(u16x4*)(cp + mt * 32 + 8 * g + 4 * hi) = o4;
      }
  }
}

// ---------------------------------------------------------------- launch
extern "C" void kernel_launch(void* const* d_in, const int* in_sizes, int n_in,
                              void* d_out, int out_size, void* d_ws, size_t ws_size,
                              hipStream_t stream) {
  const float* x    = (const float*)d_in[0];
  const float* Wqkv = (const float*)d_in[1];
  const float* bqkv = (const float*)d_in[2];
  const float* Wo   = (const float*)d_in[3];
  const float* bo   = (const float*)d_in[4];
  const int*   mask = (const int*)d_in[5];
  float* out = (float*)d_out;

  unsigned short* ws = (unsigned short*)d_ws;
  const size_t SZ_X = (size_t)8192 * 1024;  // B*T*D
  unsigned short* xb    = ws;                                   // 16 MB, reused as ctx
  unsigned short* WqkvT = xb + SZ_X;                            // 6 MB
  unsigned short* WoT   = WqkvT + (size_t)3072 * 1024;          // 2 MB
  unsigned short* Qb    = WoT + (size_t)1024 * 1024;            // 16 MB
  unsigned short* Kb    = Qb + SZ_X;                            // 16 MB
  unsigned short* Vt    = Kb + SZ_X;                            // 16 MB
  int*            kparts = (int*)(Vt + SZ_X);                   // 128 B
  unsigned short* ctx   = xb;  // xb dead after GEMM1

  static bool inited = false;
  if (!inited) {
    hipFuncSetAttribute((const void*)gemm_bt<0>,
                        hipFuncAttributeMaxDynamicSharedMemorySize, 147456);
    hipFuncSetAttribute((const void*)gemm_bt<1>,
                        hipFuncAttributeMaxDynamicSharedMemorySize, 147456);
    inited = true;
  }

  prep_fused<<<8224, 256, 0, stream>>>(x, xb, Wqkv, WqkvT, Wo, WoT, mask, kparts);
  gemm_bt<0><<<768, 512, 147456, stream>>>(xb, WqkvT, bqkv, nullptr, Qb, Kb, Vt, kparts,
                                           8192, 3072, 1024);
  flash_attn<<<1024, 256, 0, stream>>>(Qb, Kb, Vt, kparts, ctx);
  gemm_bt<1><<<256, 512, 147456, stream>>>(ctx, WoT, bo, out, nullptr, nullptr, nullptr,
                                           nullptr, 8192, 1024, 1024);
}